// Round 8
// baseline (153.242 us; speedup 1.0000x reference)
//
#include <hip/hip_runtime.h>

typedef short short8 __attribute__((ext_vector_type(8)));
typedef float f32x4 __attribute__((ext_vector_type(4)));

#define HW 3136    // 56*56
#define NPX 12544  // B*HW
#define WSTR 844   // wgt pixel stride (ushorts): 16*52 + 12 pad; 422 dw % 32 = 6
#define YSTR 96    // ytb row stride: 64 y + [1, 0..0] b2 lane
#define XS_OFF 12928  // bytes of xsb region: 16*101*8

__device__ __forceinline__ unsigned short f2bf(float f) {
    union { float f; unsigned int u; } v; v.f = f;
    unsigned int u = v.u;
    u += 0x7FFFu + ((u >> 16) & 1u);
    return (unsigned short)(u >> 16);
}

__device__ __forceinline__ float fget(const float4& v, int e) {
    return e == 0 ? v.x : e == 1 ? v.y : e == 2 ? v.z : v.w;
}

// x-footprint loads for one chunk into registers (no LDS side effects)
__device__ __forceinline__ void loadx(const float* __restrict__ x, int b, int chunk,
                                      int sg, int sr, int h0, int w0, float4 rv[4][3]) {
    int hh = h0 + sr - 3;
    if (hh >= 0 && hh < 56) {
        const float* src = x + ((size_t)b * 256 + (chunk << 6) + sg * 4) * HW + hh * 56;
#pragma unroll
        for (int qq = 0; qq < 3; ++qq) {
            int col0 = w0 - 4 + qq * 4;
            if (col0 >= 0 && col0 + 3 <= 55) {
#pragma unroll
                for (int ci = 0; ci < 4; ++ci)
                    rv[ci][qq] = *(const float4*)(src + ci * HW + col0);
            } else {
#pragma unroll
                for (int ci = 0; ci < 4; ++ci) {
                    float tmp[4];
#pragma unroll
                    for (int e = 0; e < 4; ++e) {
                        int col = col0 + e;
                        tmp[e] = (col >= 0 && col <= 55) ? src[ci * HW + col] : 0.f;
                    }
                    rv[ci][qq] = make_float4(tmp[0], tmp[1], tmp[2], tmp[3]);
                }
            }
        }
    } else {
#pragma unroll
        for (int qq = 0; qq < 3; ++qq)
#pragma unroll
            for (int ci = 0; ci < 4; ++ci)
                rv[ci][qq] = make_float4(0.f, 0.f, 0.f, 0.f);
    }
}

__device__ __forceinline__ void ldA(const unsigned short* __restrict__ w2b96,
                                    int c0, int tile, int n, int quad,
                                    short8& f0, short8& f1, short8& f2) {
    const unsigned short* ap = w2b96 + (size_t)(c0 + tile * 16 + n) * 96 + quad * 8;
    f0 = *(const short8*)(ap);
    f1 = *(const short8*)(ap + 32);
    f2 = *(const short8*)(ap + 64);
}

// Merged prep + y-GEMM.
// blocks 0..783: y = relu(bn(w1 @ x)) -> ytb[px][96] (w1 converted inline, BN inline)
// blocks 784..979: w2b96[ch][96] = bf16([w2 | b2 | 0..])
__global__ __launch_bounds__(256) void kyw(
    const float* __restrict__ x, const float* __restrict__ w1,
    const float* __restrict__ b1, const float* __restrict__ gamma,
    const float* __restrict__ beta, const float* __restrict__ mean,
    const float* __restrict__ var, const float* __restrict__ w2,
    const float* __restrict__ b2, unsigned short* __restrict__ ytb,
    unsigned short* __restrict__ w2b96)
{
    __shared__ unsigned short xt[16 * 264];    // [px][ch], stride 264
    const int t = threadIdx.x, bid = blockIdx.x;

    if (bid >= 784) {                          // w2 -> bf16 K=96 rows
        const int ch0 = (bid - 784) * 16;
#pragma unroll
        for (int i = 0; i < 6; ++i) {
            int j = i * 256 + t;               // 1536 = 16 ch * 96
            int ch = ch0 + j / 96, col = j - (j / 96) * 96;
            float v = col < 64 ? w2[ch * 64 + col] : (col == 64 ? b2[ch] : 0.f);
            w2b96[ch * 96 + col] = f2bf(v);
        }
        return;
    }

    const int px0 = bid * 16;
    const int b = px0 / HW;
    const int p0 = px0 - b * HW;

    // stage x tile: 16 px x 256 ch fp32 -> bf16 LDS (transposed to [px][ch])
#pragma unroll
    for (int i = 0; i < 4; ++i) {
        int j = i * 256 + t;                   // 1024 jobs: (c, pixel-quad)
        int c = j >> 2, pq = j & 3;
        float4 v = *(const float4*)(x + (size_t)(b * 256 + c) * HW + p0 + pq * 4);
        xt[(pq * 4 + 0) * 264 + c] = f2bf(v.x);
        xt[(pq * 4 + 1) * 264 + c] = f2bf(v.y);
        xt[(pq * 4 + 2) * 264 + c] = f2bf(v.z);
        xt[(pq * 4 + 3) * 264 + c] = f2bf(v.w);
    }
    // constant tail of ytb rows: [64]=1.0bf16, [65..95]=0
    if (t < 16) {
        unsigned short* yr = ytb + (size_t)(px0 + t) * YSTR + 64;
        ushort4 one; one.x = 0x3F80u; one.y = 0; one.z = 0; one.w = 0;
        ushort4 z; z.x = 0; z.y = 0; z.z = 0; z.w = 0;
        *(ushort4*)(yr) = one;
#pragma unroll
        for (int q = 1; q < 8; ++q) *(ushort4*)(yr + q * 4) = z;
    }
    __syncthreads();

    const int lane = t & 63, wave = t >> 6;
    const int n = lane & 15, quad = lane >> 4;
    const int m0 = wave * 16;

    f32x4 acc = {0.f, 0.f, 0.f, 0.f};
#pragma unroll
    for (int k = 0; k < 8; ++k) {
        const float* wrow = w1 + (m0 + n) * 256 + k * 32 + quad * 8;
        float4 wa = *(const float4*)(wrow);
        float4 wb = *(const float4*)(wrow + 4);
        short8 af;
        af[0] = (short)f2bf(wa.x); af[1] = (short)f2bf(wa.y);
        af[2] = (short)f2bf(wa.z); af[3] = (short)f2bf(wa.w);
        af[4] = (short)f2bf(wb.x); af[5] = (short)f2bf(wb.y);
        af[6] = (short)f2bf(wb.z); af[7] = (short)f2bf(wb.w);
        short8 bf = *(const short8*)(&xt[n * 264 + k * 32 + quad * 8]);
        acc = __builtin_amdgcn_mfma_f32_16x16x32_bf16(af, bf, acc, 0, 0, 0);
    }
    ushort4 pack;
    unsigned short pk[4];
#pragma unroll
    for (int r = 0; r < 4; ++r) {
        int m = m0 + quad * 4 + r;
        float sc = gamma[m] * rsqrtf(var[m] + 1e-5f);
        float sh = beta[m] - mean[m] * sc + b1[m] * sc;
        pk[r] = f2bf(fmaxf(acc[r] * sc + sh, 0.f));
    }
    pack.x = pk[0]; pack.y = pk[1]; pack.z = pk[2]; pack.w = pk[3];
    *(ushort4*)(ytb + (size_t)(px0 + n) * YSTR + m0 + quad * 4) = pack;
}

// One (batch, chunk) per block: w-gen (K=96 MFMA, dual-acc pipelined) + involution.
__global__ __launch_bounds__(256, 4) void kmain(
    const float* __restrict__ x, const unsigned short* __restrict__ w2b96,
    const unsigned short* __restrict__ ytb, float* __restrict__ out)
{
    __shared__ __align__(16) char smem[39936];
    uint2* xsb = (uint2*)smem;                             // 16*101 u2 = 12928 B
    unsigned short* wgt = (unsigned short*)(smem + XS_OFF);// 16*844 ush = 27008 B

    const int t = threadIdx.x;
    const int pix = t & 15, sub = t >> 4;
    const int lane = t & 63, wave = t >> 6;
    const int z = blockIdx.z;
    const int b = z >> 2, chunk = z & 3;
    const int h0 = blockIdx.y * 4, w0 = blockIdx.x * 4;
    const int ph = pix >> 2, pw = pix & 3;
    const int h = h0 + ph, w = w0 + pw;
    const int n = lane & 15, quad = lane >> 4;
    const int sg = t & 15, sr = t >> 4;       // staging job (t<160)

    // 1. prefetch x footprint for this chunk (HBM latency overlaps w-gen)
    float4 rv[4][3];
    if (t < 160) loadx(x, b, chunk, sg, sr, h0, w0, rv);

    // 2. B-fragments from ytb (L2-resident; K=96 incl. b2 lane)
    const int Pn = b * HW + (h0 + (n >> 2)) * 56 + w0 + (n & 3);
    const unsigned short* yrp = ytb + (size_t)Pn * YSTR + quad * 8;
    const short8 bf0 = *(const short8*)(yrp);
    const short8 bf1 = *(const short8*)(yrp + 32);
    const short8 bf2 = *(const short8*)(yrp + 64);

    // 3. zero wgt pad taps (k=49..51)
    for (int i = t; i < 768; i += 256) {
        int p = i / 48, rem = i - p * 48;
        int g = rem / 3, kk = 49 + (rem - g * 3);
        wgt[p * WSTR + g * 52 + kk] = 0;
    }

    // 4. commit footprint to LDS as packed bf16x4 (frees rv before w-gen)
    if (t < 160) {
        uint2* dst = &xsb[sg * 101 + sr * 10];
#pragma unroll
        for (int s = 0; s < 10; ++s) {
            int qq = (s + 1) >> 2, e = (s + 1) & 3;
            uint2 pkx;
            pkx.x = (unsigned int)f2bf(fget(rv[0][qq], e)) |
                    ((unsigned int)f2bf(fget(rv[1][qq], e)) << 16);
            pkx.y = (unsigned int)f2bf(fget(rv[2][qq], e)) |
                    ((unsigned int)f2bf(fget(rv[3][qq], e)) << 16);
            dst[s] = pkx;
        }
    }

    // 5. weight generation: 784 ch x 16 px, K=96 MFMA.
    //    Dual accumulator: tile pair (i0, i1=i0+4) per step, prefetch next pair.
    const int c0 = chunk * 784;
    {
        short8 a00, a01, a02, a10, a11, a12;
        int i0 = wave, i1 = wave + 4;
        ldA(w2b96, c0, i0, n, quad, a00, a01, a02);
        ldA(w2b96, c0, i1, n, quad, a10, a11, a12);
        for (; i0 < 49; i0 += 8, i1 += 8) {
            short8 c00 = a00, c01 = a01, c02 = a02;
            short8 c10 = a10, c11 = a11, c12 = a12;
            const bool has1 = (i1 < 49);
            if (i0 + 8 < 49) ldA(w2b96, c0, i0 + 8, n, quad, a00, a01, a02);
            if (i1 + 8 < 49) ldA(w2b96, c0, i1 + 8, n, quad, a10, a11, a12);
            f32x4 acc0 = {0.f, 0.f, 0.f, 0.f};
            f32x4 acc1 = {0.f, 0.f, 0.f, 0.f};
            acc0 = __builtin_amdgcn_mfma_f32_16x16x32_bf16(c00, bf0, acc0, 0, 0, 0);
            if (has1) acc1 = __builtin_amdgcn_mfma_f32_16x16x32_bf16(c10, bf0, acc1, 0, 0, 0);
            acc0 = __builtin_amdgcn_mfma_f32_16x16x32_bf16(c01, bf1, acc0, 0, 0, 0);
            if (has1) acc1 = __builtin_amdgcn_mfma_f32_16x16x32_bf16(c11, bf1, acc1, 0, 0, 0);
            acc0 = __builtin_amdgcn_mfma_f32_16x16x32_bf16(c02, bf2, acc0, 0, 0, 0);
            if (has1) acc1 = __builtin_amdgcn_mfma_f32_16x16x32_bf16(c12, bf2, acc1, 0, 0, 0);
            int rb0 = i0 * 16 + quad * 4;
#pragma unroll
            for (int r = 0; r < 4; ++r) {
                int chl = rb0 + r;
                int g = chl / 49;
                int kk = chl - g * 49;
                wgt[n * WSTR + g * 52 + kk] = f2bf(acc0[r]);
            }
            if (has1) {
                int rb1 = i1 * 16 + quad * 4;
#pragma unroll
                for (int r = 0; r < 4; ++r) {
                    int chl = rb1 + r;
                    int g = chl / 49;
                    int kk = chl - g * 49;
                    wgt[n * WSTR + g * 52 + kk] = f2bf(acc1[r]);
                }
            }
        }
    }
    __syncthreads();    // the only barrier: xsb + wgt ready

    // 6. involution: thread = (group sub, 4 channels, pixel pix)
    const unsigned short* wr = &wgt[pix * WSTR + sub * 52];
    const uint2* xr = &xsb[sub * 101];
    float a0 = 0.f, a1 = 0.f, a2 = 0.f, a3 = 0.f;
#pragma unroll
    for (int kq = 0; kq < 13; ++kq) {
        uint2 wp = *(const uint2*)(wr + kq * 4);
#pragma unroll
        for (int e = 0; e < 4; ++e) {
            int k = kq * 4 + e;
            if (k < 49) {
                unsigned int uw = (e < 2) ? wp.x : wp.y;
                unsigned int ub = (e & 1) ? (uw & 0xffff0000u) : (uw << 16);
                float wv = __uint_as_float(ub);
                int ki = k / 7, kj = k - ki * 7;       // compile-time
                uint2 xp = xr[(ph + ki) * 10 + (pw + kj)];
                a0 += wv * __uint_as_float(xp.x << 16);
                a1 += wv * __uint_as_float(xp.x & 0xffff0000u);
                a2 += wv * __uint_as_float(xp.y << 16);
                a3 += wv * __uint_as_float(xp.y & 0xffff0000u);
            }
        }
    }
    size_t ob = ((size_t)b * 256 + chunk * 64 + sub * 4) * HW + h * 56 + w;
    out[ob] = a0;
    out[ob + HW] = a1;
    out[ob + 2 * HW] = a2;
    out[ob + 3 * HW] = a3;
}

extern "C" void kernel_launch(void* const* d_in, const int* in_sizes, int n_in,
                              void* d_out, int out_size, void* d_ws, size_t ws_size,
                              hipStream_t stream) {
    const float* x     = (const float*)d_in[0];
    const float* w1    = (const float*)d_in[1];
    const float* b1    = (const float*)d_in[2];
    const float* gamma = (const float*)d_in[3];
    const float* beta  = (const float*)d_in[4];
    const float* mean  = (const float*)d_in[5];
    const float* var   = (const float*)d_in[6];
    const float* w2    = (const float*)d_in[7];
    const float* b2    = (const float*)d_in[8];
    float* out = (float*)d_out;

    unsigned short* ytb   = (unsigned short*)d_ws;         // 12544*96 = 1204224 ush
    unsigned short* w2b96 = ytb + (size_t)NPX * YSTR;      // 3136*96  = 301056 ush

    hipLaunchKernelGGL(kyw, dim3(980), dim3(256), 0, stream,
                       x, w1, b1, gamma, beta, mean, var, w2, b2, ytb, w2b96);
    hipLaunchKernelGGL(kmain, dim3(14, 14, 16), dim3(256), 0, stream,
                       x, w2b96, ytb, out);
}